// Round 1
// 1320.687 us; speedup vs baseline: 1.1742x; 1.1742x over previous
//
#include <hip/hip_runtime.h>
#include <hip/hip_bf16.h>
#include <stdint.h>

typedef __bf16 bf16;
typedef __bf16 bf16x8 __attribute__((ext_vector_type(8)));
typedef float f32x4 __attribute__((ext_vector_type(4)));

struct P22 { const void* p[22]; };
struct I22 { int n[22]; };

__device__ inline float bf2f(bf16 b) { return (float)b; }

// flag-dispatched scalar load: tensor may be bf16 (flag=0) or fp32 (flag=1)
__device__ inline float gld(const void* p, long i, int f32) {
    return f32 ? ((const float*)p)[i] : bf2f(((const bf16*)p)[i]);
}
// 8 contiguous elements -> bf16x8 (MFMA operand)
__device__ inline bf16x8 gld8(const void* p, long i, int f32) {
    bf16x8 r;
    if (f32) {
        const float* q = (const float*)p + i;
        f32x4 a = *(const f32x4*)q, b = *(const f32x4*)(q + 4);
        #pragma unroll
        for (int j = 0; j < 4; ++j) { r[j] = (bf16)a[j]; r[4 + j] = (bf16)b[j]; }
    } else {
        r = *reinterpret_cast<const bf16x8*>((const bf16*)p + i);
    }
    return r;
}
// 8 contiguous elements -> float[8], full precision for fp32 inputs
__device__ inline void ld8f(const void* p, long i, int f32, float* o) {
    if (f32) {
        const float* q = (const float*)p + i;
        f32x4 a = *(const f32x4*)q, b = *(const f32x4*)(q + 4);
        #pragma unroll
        for (int j = 0; j < 4; ++j) { o[j] = a[j]; o[4 + j] = b[j]; }
    } else {
        bf16x8 r = *reinterpret_cast<const bf16x8*>((const bf16*)p + i);
        #pragma unroll
        for (int j = 0; j < 8; ++j) o[j] = bf2f(r[j]);
    }
}
__device__ inline float fin(float v) { return isfinite(v) ? v : 0.f; }

// ---- per-tensor dtype detection (unchanged) ----
__global__ void k_detect(P22 in, I22 sz, int* flags) {
    int t = blockIdx.x;
    if (t == 2 || t == 3) { if (threadIdx.x == 0) flags[t] = 0; return; }  // int tensors
    const unsigned short* u = (const unsigned short*)in.p[t];
    int pairs = sz.n[t] >> 1; if (pairs > 256) pairs = 256;
    int lane = threadIdx.x;  // blockDim = 64
    int insane = 0, evenNZ = 0, oddNZ = 0;
    for (int i = lane; i < pairs; i += 64) {
        unsigned short e = u[2 * i], o = u[2 * i + 1];
        int ee = (e >> 7) & 0xFF;
        if (e != 0) { evenNZ++; if (ee > 133 || ee < 108) insane++; }
        if (o != 0) oddNZ++;
    }
    #pragma unroll
    for (int off = 1; off < 64; off <<= 1) {
        insane += __shfl_xor(insane, off, 64);
        evenNZ += __shfl_xor(evenNZ, off, 64);
        oddNZ  += __shfl_xor(oddNZ,  off, 64);
    }
    if (lane == 0) {
        int f32 = 0;
        if (insane * 4 > pairs) f32 = 1;
        else if (evenNZ == 0 && oddNZ > 0) f32 = 1;
        flags[t] = f32;
    }
}

// ---- prep: Wcat = [W_sg | W_dg | W_du | W_su@W_gat] (bf16, 64x256), bcat fp32 ----
__global__ void k_prep(P22 in, const int* F, bf16* Wcat, float* bcat) {
    int j = threadIdx.x;
    int sec = j >> 6, jc = j & 63;
    if (sec < 3) {
        int wi = sec == 0 ? 4 : (sec == 1 ? 6 : 12);
        const void* W = in.p[wi]; int fW = F[wi];
        for (int k = 0; k < 64; ++k) Wcat[k * 256 + j] = (bf16)gld(W, k * 64 + jc, fW);
        bcat[j] = gld(in.p[wi + 1], jc, F[wi + 1]);
    } else {
        const void* Wsu = in.p[10]; int f1 = F[10];
        const void* Wg  = in.p[14]; int f2 = F[14];
        for (int k = 0; k < 64; ++k) {
            float acc = 0.f;
            for (int t = 0; t < 64; ++t) acc += gld(Wsu, k * 64 + t, f1) * gld(Wg, t * 64 + jc, f2);
            Wcat[k * 256 + j] = (bf16)acc;
        }
        float acc = gld(in.p[15], jc, F[15]);  // b_gat
        for (int t = 0; t < 64; ++t) acc += gld(in.p[11], t, F[11]) * gld(Wg, t * 64 + jc, f2);
        bcat[j] = acc;
    }
}

// ---- node GEMM: NT[N][256] = node_feats @ Wcat + bcat (bf16 out) ----
__global__ void __launch_bounds__(256) k_node_gemm(P22 in, const int* F, const bf16* Wcat,
                                                   const float* bcat, bf16* NT, int N) {
    int f0 = F[0];
    int lane = threadIdx.x & 63;
    int w = threadIdx.x >> 6;
    int col0 = w * 64, q = lane >> 4, li = lane & 15;
    bf16x8 bfr[4][2];
    #pragma unroll
    for (int t = 0; t < 4; ++t)
        #pragma unroll
        for (int h = 0; h < 2; ++h)
            #pragma unroll
            for (int j = 0; j < 8; ++j)
                bfr[t][h][j] = Wcat[(long)(h * 32 + q * 8 + j) * 256 + col0 + t * 16 + li];
    float bias[4];
    #pragma unroll
    for (int t = 0; t < 4; ++t) bias[t] = bcat[col0 + t * 16 + li];

    int ntiles = (N + 15) >> 4;
    for (int rt = blockIdx.x; rt < ntiles; rt += gridDim.x) {
        int row0 = rt * 16;
        int rload = min(row0 + li, N - 1);
        bf16x8 a0 = gld8(in.p[0], (long)rload * 64 + (q << 3), f0);
        bf16x8 a1 = gld8(in.p[0], (long)rload * 64 + 32 + (q << 3), f0);
        #pragma unroll
        for (int t = 0; t < 4; ++t) {
            f32x4 acc = {0.f, 0.f, 0.f, 0.f};
            acc = __builtin_amdgcn_mfma_f32_16x16x32_bf16(a0, bfr[t][0], acc, 0, 0, 0);
            acc = __builtin_amdgcn_mfma_f32_16x16x32_bf16(a1, bfr[t][1], acc, 0, 0, 0);
            int col = col0 + t * 16 + li;
            #pragma unroll
            for (int r = 0; r < 4; ++r) {
                int row = row0 + q * 4 + r;
                if (row < N) NT[(long)row * 256 + col] = (bf16)(acc[r] + bias[t]);
            }
        }
    }
}

// ---- el/er: [N][2] attention dots from feat = NT cols 192..255 ----
__global__ void k_elr(P22 in, const int* F, const bf16* NT, float* el, float* er, int N) {
    int lane = threadIdx.x & 63;
    int slot = threadIdx.x >> 6;
    int h = lane >> 5, dh = lane & 31;
    float al = gld(in.p[16], h * 32 + dh, F[16]);
    float ar = gld(in.p[17], h * 32 + dh, F[17]);
    for (int n = blockIdx.x * 4 + slot; n < N; n += gridDim.x * 4) {
        float f = bf2f(NT[(long)n * 256 + 192 + lane]);
        float pl = f * al, pr = f * ar;
        #pragma unroll
        for (int off = 1; off < 32; off <<= 1) {
            pl += __shfl_xor(pl, off, 64);
            pr += __shfl_xor(pr, off, 64);
        }
        if (dh == 0) { el[n * 2 + h] = pl; er[n * 2 + h] = pr; }
    }
}

// ---- edge GEMM: Meg[E][64] = edge_feats @ W_eg + b_eg (bf16, streaming MFMA) ----
__global__ void __launch_bounds__(256) k_edge_gemm(P22 in, const int* F, bf16* Meg, int E) {
    int f_ef = F[1];
    int lane = threadIdx.x & 63;
    int w = threadIdx.x >> 6;
    int q = lane >> 4, li = lane & 15;
    bf16x8 bfrag[4][2];
    #pragma unroll
    for (int t = 0; t < 4; ++t)
        #pragma unroll
        for (int h = 0; h < 2; ++h)
            #pragma unroll
            for (int j = 0; j < 8; ++j)
                bfrag[t][h][j] = (bf16)gld(in.p[8], (long)(h * 32 + q * 8 + j) * 64 + t * 16 + li, F[8]);
    float bias[4];
    #pragma unroll
    for (int t = 0; t < 4; ++t) bias[t] = gld(in.p[9], t * 16 + li, F[9]);

    int ntiles = E >> 4;   // E divisible by 16
    for (int et = blockIdx.x * 4 + w; et < ntiles; et += gridDim.x * 4) {
        int e0 = et * 16;
        bf16x8 a0 = gld8(in.p[1], (long)(e0 + li) * 64 + (q << 3), f_ef);
        bf16x8 a1 = gld8(in.p[1], (long)(e0 + li) * 64 + 32 + (q << 3), f_ef);
        #pragma unroll
        for (int t = 0; t < 4; ++t) {
            f32x4 c = {0.f, 0.f, 0.f, 0.f};
            c = __builtin_amdgcn_mfma_f32_16x16x32_bf16(a0, bfrag[t][0], c, 0, 0, 0);
            c = __builtin_amdgcn_mfma_f32_16x16x32_bf16(a1, bfrag[t][1], c, 0, 0, 0);
            #pragma unroll
            for (int r = 0; r < 4; ++r) {
                int row = e0 + q * 4 + r;
                Meg[(long)row * 64 + t * 16 + li] = (bf16)(c[r] + bias[t]);
            }
        }
    }
}

// ---- CSR build: deg -> exclusive scan -> bucket scatter ----
__global__ void k_deg(const int* dst, int* deg, int E) {
    for (int e = blockIdx.x * blockDim.x + threadIdx.x; e < E; e += gridDim.x * blockDim.x)
        atomicAdd(&deg[dst[e]], 1);
}

__global__ void __launch_bounds__(1024) k_scan(const int* deg, int* rowptr, int* cursor, int N) {
    __shared__ int sums[1024];
    int t = threadIdx.x;
    int chunk = (N + 1023) >> 10;
    int lo = t * chunk, hi = min(lo + chunk, N);
    int s = 0;
    for (int i = lo; i < hi; ++i) s += deg[i];
    int val = s;
    sums[t] = val;
    __syncthreads();
    for (int off = 1; off < 1024; off <<= 1) {
        int add = (t >= off) ? sums[t - off] : 0;
        __syncthreads();
        val += add; sums[t] = val;
        __syncthreads();
    }
    int run = val - s;  // exclusive prefix
    for (int i = lo; i < hi; ++i) {
        rowptr[i] = run; cursor[i] = run;
        run += deg[i];
    }
    if (t == 1023) rowptr[N] = run;  // == E
}

__global__ void k_scatter(const int* dst, int* cursor, int* eidx, int E) {
    for (int e = blockIdx.x * blockDim.x + threadIdx.x; e < E; e += gridDim.x * blockDim.x) {
        int pos = atomicAdd(&cursor[dst[e]], 1);
        eidx[pos] = e;
    }
}

// ---- dst-owned aggregation: one wave per node, all sums in registers ----
// Produces v[N][64] = hagg + gat + b_gat, plus BN-e and BN-n stats (block-reduced).
__global__ void __launch_bounds__(256) k_agg(
    P22 in, const int* F, const bf16* NT, const bf16* Meg,
    const float* el, const float* er, const int* rowptr, const int* eidx,
    float* v, float* bn_e_acc, float* bn_n_acc, int N) {
    int lane = threadIdx.x & 63;
    int w = threadIdx.x >> 6;
    int c = lane, h = c >> 5;
    const int* srcp = (const int*)in.p[2];
    float bg = gld(in.p[15], c, F[15]);
    float es = 0.f, eq = 0.f;   // BN-e sums (per col)
    float vs = 0.f, vq = 0.f;   // BN-n sums (per col)

    for (int n = blockIdx.x * 4 + w; n < N; n += gridDim.x * 4) {
        float dn = bf2f(NT[(long)n * 256 + 64 + c]);   // e_dst row of this node
        float errh = er[(long)n * 2 + h];
        int lo = rowptr[n], hi = rowptr[n + 1];
        float ss = 0.f, ssh = 0.f, num = 0.f, den = 0.f;
        auto do_edge = [&](int e) {
            int si = srcp[e];
            const bf16* srow = NT + (long)si * 256;
            float mg  = bf2f(Meg[(long)e * 64 + c]);
            float srv = bf2f(srow[c]);
            float bh  = bf2f(srow[128 + c]);
            float ft  = bf2f(srow[192 + c]);
            float mv = mg + srv + dn;
            float sg = 1.f / (1.f + __expf(-mv));
            ss += sg; ssh += bh * sg;
            es += mv; eq += mv * mv;
            float lg = el[(long)si * 2 + h] + errh;
            lg = lg > 0.f ? lg : 0.2f * lg;
            lg = fminf(fmaxf(lg, -30.f), 30.f);
            float ex = __expf(lg);
            den += ex; num += ft * ex;  // den identical across lanes of a head
        };
        #pragma unroll 2
        for (int j = lo; j < hi; ++j) do_edge(eidx[j]);
        float hagg = ssh / (ss + 1e-6f);
        float gat = den > 0.f ? num / den : 0.f;   // zero in-degree safety
        float vv = hagg + gat + bg;
        v[(long)n * 64 + c] = vv;
        vs += vv; vq += vv * vv;
    }

    __shared__ float r1[256], r2[256];
    r1[threadIdx.x] = es; r2[threadIdx.x] = eq;
    __syncthreads();
    if (threadIdx.x < 64) {
        atomicAdd(bn_e_acc + c,      r1[c] + r1[64 + c] + r1[128 + c] + r1[192 + c]);
        atomicAdd(bn_e_acc + 64 + c, r2[c] + r2[64 + c] + r2[128 + c] + r2[192 + c]);
    }
    __syncthreads();
    r1[threadIdx.x] = vs; r2[threadIdx.x] = vq;
    __syncthreads();
    if (threadIdx.x < 64) {
        atomicAdd(bn_n_acc + c,      r1[c] + r1[64 + c] + r1[128 + c] + r1[192 + c]);
        atomicAdd(bn_n_acc + 64 + c, r2[c] + r2[64 + c] + r2[128 + c] + r2[192 + c]);
    }
}

// ---- x output: x = node + silu(BN_n(v)) ----
__global__ void k_x_out(P22 in, const int* F, const float* v, const float* acc,
                        void* d_out, int N) {
    int f_out = F[0];
    int c = threadIdx.x & 63;
    int slot = threadIdx.x >> 6;
    float inv = 1.f / (float)N;
    float mean = acc[c] * inv;
    float var = fmaxf(acc[64 + c] * inv - mean * mean, 0.f);
    float rstd = rsqrtf(var + 1e-5f);
    float ga = gld(in.p[18], c, F[18]), be = gld(in.p[19], c, F[19]);
    for (int n = blockIdx.x * 4 + slot; n < N; n += gridDim.x * 4) {
        float t = (v[(long)n * 64 + c] - mean) * rstd * ga + be;
        float sl = t / (1.f + __expf(-t));
        float x = fin(gld(in.p[0], (long)n * 64 + c, F[0]) + sl);
        if (f_out) ((float*)d_out)[(long)n * 64 + c] = x;
        else       ((bf16*)d_out)[(long)n * 64 + c] = (bf16)x;
    }
}

// ---- edge output: y = ef + silu(BN_e(m)), pure streaming (no MFMA) ----
// thread handles 8 cols of one edge; Meg/NT/ef vector loads, vector store.
__global__ void __launch_bounds__(256) k_edge_y(
    P22 in, const int* F, const bf16* NT, const bf16* Meg,
    const float* bn_e_acc, void* d_out, int N, int E) {
    int f_ef = F[1], f_out = F[0];
    const int* srcp = (const int*)in.p[2];
    const int* dstp = (const int*)in.p[3];
    int tid = blockIdx.x * 256 + threadIdx.x;
    int oc = tid & 7, c0 = oc * 8;        // constant per thread (stride multiple of 8)
    float mean[8], rstd[8], ga[8], be[8];
    float invE = 1.f / (float)E;
    #pragma unroll
    for (int j = 0; j < 8; ++j) {
        int c = c0 + j;
        float mn = bn_e_acc[c] * invE;
        float vr = fmaxf(bn_e_acc[64 + c] * invE - mn * mn, 0.f);
        mean[j] = mn; rstd[j] = rsqrtf(vr + 1e-5f);
        ga[j] = gld(in.p[20], c, F[20]); be[j] = gld(in.p[21], c, F[21]);
    }
    char* yb = (char*)d_out + (size_t)N * 64 * (f_out ? 4 : 2);
    int estride = (gridDim.x * 256) >> 3;
    for (long e = tid >> 3; e < E; e += estride) {
        int si = srcp[e], di = dstp[e];
        bf16x8 mg = *reinterpret_cast<const bf16x8*>(Meg + e * 64 + c0);
        bf16x8 sr = *reinterpret_cast<const bf16x8*>(NT + (long)si * 256 + c0);
        bf16x8 dr = *reinterpret_cast<const bf16x8*>(NT + (long)di * 256 + 64 + c0);
        float ef[8]; ld8f(in.p[1], e * 64 + c0, f_ef, ef);
        float y[8];
        #pragma unroll
        for (int j = 0; j < 8; ++j) {
            float mv = bf2f(mg[j]) + bf2f(sr[j]) + bf2f(dr[j]);
            float t = (mv - mean[j]) * rstd[j] * ga[j] + be[j];
            float sl = t / (1.f + __expf(-t));
            y[j] = fin(ef[j] + sl);
        }
        if (f_out) {
            float* yp = (float*)yb + e * 64 + c0;
            f32x4 y0 = {y[0], y[1], y[2], y[3]}, y1 = {y[4], y[5], y[6], y[7]};
            *(f32x4*)yp = y0; *(f32x4*)(yp + 4) = y1;
        } else {
            bf16x8 yv;
            #pragma unroll
            for (int j = 0; j < 8; ++j) yv[j] = (bf16)y[j];
            *reinterpret_cast<bf16x8*>((bf16*)yb + e * 64 + c0) = yv;
        }
    }
}

extern "C" void kernel_launch(void* const* d_in, const int* in_sizes, int n_in,
                              void* d_out, int out_size, void* d_ws, size_t ws_size,
                              hipStream_t stream) {
    P22 p; I22 sz;
    for (int i = 0; i < 22; ++i) { p.p[i] = d_in[i]; sz.n[i] = in_sizes[i]; }
    const int N = in_sizes[0] / 64;
    const int E = in_sizes[2];

    char* ws = (char*)d_ws;
    size_t off = 0;
    auto alloc = [&](size_t bytes) -> void* {
        void* ptr = ws + off;
        off = (off + bytes + 255) & ~(size_t)255;
        return ptr;
    };
    int*   flags  = (int*)  alloc(22 * 4);
    bf16*  NT     = (bf16*) alloc((size_t)N * 256 * 2);   // [e_src|e_dst|Bh|feat] bf16
    float* el     = (float*)alloc((size_t)N * 2 * 4);
    float* er     = (float*)alloc((size_t)N * 2 * 4);
    bf16*  Wcat   = (bf16*) alloc(64 * 256 * 2);
    float* bcat   = (float*)alloc(256 * 4);
    bf16*  Meg    = (bf16*) alloc((size_t)E * 64 * 2);    // edge GEMM result
    int*   rowptr = (int*)  alloc((size_t)(N + 1) * 4);
    int*   cursor = (int*)  alloc((size_t)N * 4);
    int*   eidx   = (int*)  alloc((size_t)E * 4);
    float* v      = (float*)alloc((size_t)N * 64 * 4);    // pre-BN node values
    char* zbase = ws + off;
    int*   deg      = (int*)  alloc((size_t)N * 4);
    float* bn_e_acc = (float*)alloc(128 * 4);
    float* bn_n_acc = (float*)alloc(128 * 4);
    size_t zbytes = (size_t)((ws + off) - zbase);
    hipMemsetAsync(zbase, 0, zbytes, stream);

    const int* dstp = (const int*)d_in[3];

    hipLaunchKernelGGL(k_detect, dim3(22), dim3(64), 0, stream, p, sz, flags);
    hipLaunchKernelGGL(k_prep, dim3(1), dim3(256), 0, stream, p, flags, Wcat, bcat);
    hipLaunchKernelGGL(k_node_gemm, dim3(800), dim3(256), 0, stream, p, flags, Wcat, bcat, NT, N);
    hipLaunchKernelGGL(k_elr, dim3(512), dim3(256), 0, stream, p, flags, NT, el, er, N);
    hipLaunchKernelGGL(k_edge_gemm, dim3(1024), dim3(256), 0, stream, p, flags, Meg, E);
    hipLaunchKernelGGL(k_deg, dim3(1024), dim3(256), 0, stream, dstp, deg, E);
    hipLaunchKernelGGL(k_scan, dim3(1), dim3(1024), 0, stream, deg, rowptr, cursor, N);
    hipLaunchKernelGGL(k_scatter, dim3(1024), dim3(256), 0, stream, dstp, cursor, eidx, E);
    hipLaunchKernelGGL(k_agg, dim3(2048), dim3(256), 0, stream,
                       p, flags, NT, Meg, el, er, rowptr, eidx, v, bn_e_acc, bn_n_acc, N);
    hipLaunchKernelGGL(k_x_out, dim3(512), dim3(256), 0, stream, p, flags, v, bn_n_acc, d_out, N);
    hipLaunchKernelGGL(k_edge_y, dim3(2048), dim3(256), 0, stream,
                       p, flags, NT, Meg, bn_e_acc, d_out, N, E);
}

// Round 2
// 961.446 us; speedup vs baseline: 1.6130x; 1.3736x over previous
//
#include <hip/hip_runtime.h>
#include <hip/hip_bf16.h>
#include <stdint.h>

typedef __bf16 bf16;
typedef __bf16 bf16x8 __attribute__((ext_vector_type(8)));
typedef float f32x4 __attribute__((ext_vector_type(4)));

struct P22 { const void* p[22]; };
struct I22 { int n[22]; };

__device__ inline float bf2f(bf16 b) { return (float)b; }

// flag-dispatched scalar load: tensor may be bf16 (flag=0) or fp32 (flag=1)
__device__ inline float gld(const void* p, long i, int f32) {
    return f32 ? ((const float*)p)[i] : bf2f(((const bf16*)p)[i]);
}
// 8 contiguous elements -> bf16x8 (MFMA operand)
__device__ inline bf16x8 gld8(const void* p, long i, int f32) {
    bf16x8 r;
    if (f32) {
        const float* q = (const float*)p + i;
        f32x4 a = *(const f32x4*)q, b = *(const f32x4*)(q + 4);
        #pragma unroll
        for (int j = 0; j < 4; ++j) { r[j] = (bf16)a[j]; r[4 + j] = (bf16)b[j]; }
    } else {
        r = *reinterpret_cast<const bf16x8*>((const bf16*)p + i);
    }
    return r;
}
// 8 contiguous elements -> float[8], full precision for fp32 inputs
__device__ inline void ld8f(const void* p, long i, int f32, float* o) {
    if (f32) {
        const float* q = (const float*)p + i;
        f32x4 a = *(const f32x4*)q, b = *(const f32x4*)(q + 4);
        #pragma unroll
        for (int j = 0; j < 4; ++j) { o[j] = a[j]; o[4 + j] = b[j]; }
    } else {
        bf16x8 r = *reinterpret_cast<const bf16x8*>((const bf16*)p + i);
        #pragma unroll
        for (int j = 0; j < 8; ++j) o[j] = bf2f(r[j]);
    }
}
__device__ inline float fin(float v) { return isfinite(v) ? v : 0.f; }

// ---- per-tensor dtype detection (unchanged) ----
__global__ void k_detect(P22 in, I22 sz, int* flags) {
    int t = blockIdx.x;
    if (t == 2 || t == 3) { if (threadIdx.x == 0) flags[t] = 0; return; }  // int tensors
    const unsigned short* u = (const unsigned short*)in.p[t];
    int pairs = sz.n[t] >> 1; if (pairs > 256) pairs = 256;
    int lane = threadIdx.x;  // blockDim = 64
    int insane = 0, evenNZ = 0, oddNZ = 0;
    for (int i = lane; i < pairs; i += 64) {
        unsigned short e = u[2 * i], o = u[2 * i + 1];
        int ee = (e >> 7) & 0xFF;
        if (e != 0) { evenNZ++; if (ee > 133 || ee < 108) insane++; }
        if (o != 0) oddNZ++;
    }
    #pragma unroll
    for (int off = 1; off < 64; off <<= 1) {
        insane += __shfl_xor(insane, off, 64);
        evenNZ += __shfl_xor(evenNZ, off, 64);
        oddNZ  += __shfl_xor(oddNZ,  off, 64);
    }
    if (lane == 0) {
        int f32 = 0;
        if (insane * 4 > pairs) f32 = 1;
        else if (evenNZ == 0 && oddNZ > 0) f32 = 1;
        flags[t] = f32;
    }
}

// ---- prep: Wcat = [W_sg | W_dg | W_du | W_su@W_gat] (bf16, 64x256), bcat fp32 ----
// W_su/W_gat staged to LDS; the 64x64x64 fold runs from LDS (was 422 us of
// serial scalar global loads; now ~10 us).
__global__ void __launch_bounds__(256) k_prep(P22 in, const int* F, bf16* Wcat, float* bcat) {
    __shared__ float sWsu[64 * 64];
    __shared__ float sWg[64 * 64];
    int tid = threadIdx.x;
    {
        int f1 = F[10], f2 = F[14];
        #pragma unroll 4
        for (int i = tid; i < 4096; i += 256) {
            sWsu[i] = gld(in.p[10], i, f1);
            sWg[i]  = gld(in.p[14], i, f2);
        }
    }
    __syncthreads();
    int j = tid;
    int sec = j >> 6, jc = j & 63;
    if (sec < 3) {
        int wi = sec == 0 ? 4 : (sec == 1 ? 6 : 12);
        const void* W = in.p[wi]; int fW = F[wi];
        #pragma unroll 8
        for (int k = 0; k < 64; ++k) Wcat[k * 256 + j] = (bf16)gld(W, k * 64 + jc, fW);
        bcat[j] = gld(in.p[wi + 1], jc, F[wi + 1]);
    } else {
        #pragma unroll 2
        for (int k = 0; k < 64; ++k) {
            float acc = 0.f;
            #pragma unroll 8
            for (int t = 0; t < 64; ++t) acc += sWsu[k * 64 + t] * sWg[t * 64 + jc];
            Wcat[k * 256 + j] = (bf16)acc;
        }
        float acc = gld(in.p[15], jc, F[15]);  // b_gat
        #pragma unroll 8
        for (int t = 0; t < 64; ++t) acc += gld(in.p[11], t, F[11]) * sWg[t * 64 + jc];
        bcat[j] = acc;
    }
}

// ---- node GEMM: NT[N][256] = node_feats @ Wcat + bcat (bf16 out) ----
__global__ void __launch_bounds__(256) k_node_gemm(P22 in, const int* F, const bf16* Wcat,
                                                   const float* bcat, bf16* NT, int N) {
    int f0 = F[0];
    int lane = threadIdx.x & 63;
    int w = threadIdx.x >> 6;
    int col0 = w * 64, q = lane >> 4, li = lane & 15;
    bf16x8 bfr[4][2];
    #pragma unroll
    for (int t = 0; t < 4; ++t)
        #pragma unroll
        for (int h = 0; h < 2; ++h)
            #pragma unroll
            for (int j = 0; j < 8; ++j)
                bfr[t][h][j] = Wcat[(long)(h * 32 + q * 8 + j) * 256 + col0 + t * 16 + li];
    float bias[4];
    #pragma unroll
    for (int t = 0; t < 4; ++t) bias[t] = bcat[col0 + t * 16 + li];

    int ntiles = (N + 15) >> 4;
    for (int rt = blockIdx.x; rt < ntiles; rt += gridDim.x) {
        int row0 = rt * 16;
        int rload = min(row0 + li, N - 1);
        bf16x8 a0 = gld8(in.p[0], (long)rload * 64 + (q << 3), f0);
        bf16x8 a1 = gld8(in.p[0], (long)rload * 64 + 32 + (q << 3), f0);
        #pragma unroll
        for (int t = 0; t < 4; ++t) {
            f32x4 acc = {0.f, 0.f, 0.f, 0.f};
            acc = __builtin_amdgcn_mfma_f32_16x16x32_bf16(a0, bfr[t][0], acc, 0, 0, 0);
            acc = __builtin_amdgcn_mfma_f32_16x16x32_bf16(a1, bfr[t][1], acc, 0, 0, 0);
            int col = col0 + t * 16 + li;
            #pragma unroll
            for (int r = 0; r < 4; ++r) {
                int row = row0 + q * 4 + r;
                if (row < N) NT[(long)row * 256 + col] = (bf16)(acc[r] + bias[t]);
            }
        }
    }
}

// ---- el/er: [N][2] attention dots from feat = NT cols 192..255 ----
__global__ void k_elr(P22 in, const int* F, const bf16* NT, float* el, float* er, int N) {
    int lane = threadIdx.x & 63;
    int slot = threadIdx.x >> 6;
    int h = lane >> 5, dh = lane & 31;
    float al = gld(in.p[16], h * 32 + dh, F[16]);
    float ar = gld(in.p[17], h * 32 + dh, F[17]);
    for (int n = blockIdx.x * 4 + slot; n < N; n += gridDim.x * 4) {
        float f = bf2f(NT[(long)n * 256 + 192 + lane]);
        float pl = f * al, pr = f * ar;
        #pragma unroll
        for (int off = 1; off < 32; off <<= 1) {
            pl += __shfl_xor(pl, off, 64);
            pr += __shfl_xor(pr, off, 64);
        }
        if (dh == 0) { el[n * 2 + h] = pl; er[n * 2 + h] = pr; }
    }
}

// ---- edge GEMM: Meg[E][64] = edge_feats @ W_eg + b_eg (bf16, streaming MFMA) ----
__global__ void __launch_bounds__(256) k_edge_gemm(P22 in, const int* F, bf16* Meg, int E) {
    int f_ef = F[1];
    int lane = threadIdx.x & 63;
    int w = threadIdx.x >> 6;
    int q = lane >> 4, li = lane & 15;
    bf16x8 bfrag[4][2];
    #pragma unroll
    for (int t = 0; t < 4; ++t)
        #pragma unroll
        for (int h = 0; h < 2; ++h)
            #pragma unroll
            for (int j = 0; j < 8; ++j)
                bfrag[t][h][j] = (bf16)gld(in.p[8], (long)(h * 32 + q * 8 + j) * 64 + t * 16 + li, F[8]);
    float bias[4];
    #pragma unroll
    for (int t = 0; t < 4; ++t) bias[t] = gld(in.p[9], t * 16 + li, F[9]);

    int ntiles = E >> 4;   // E divisible by 16
    for (int et = blockIdx.x * 4 + w; et < ntiles; et += gridDim.x * 4) {
        int e0 = et * 16;
        bf16x8 a0 = gld8(in.p[1], (long)(e0 + li) * 64 + (q << 3), f_ef);
        bf16x8 a1 = gld8(in.p[1], (long)(e0 + li) * 64 + 32 + (q << 3), f_ef);
        #pragma unroll
        for (int t = 0; t < 4; ++t) {
            f32x4 c = {0.f, 0.f, 0.f, 0.f};
            c = __builtin_amdgcn_mfma_f32_16x16x32_bf16(a0, bfrag[t][0], c, 0, 0, 0);
            c = __builtin_amdgcn_mfma_f32_16x16x32_bf16(a1, bfrag[t][1], c, 0, 0, 0);
            #pragma unroll
            for (int r = 0; r < 4; ++r) {
                int row = e0 + q * 4 + r;
                Meg[(long)row * 64 + t * 16 + li] = (bf16)(c[r] + bias[t]);
            }
        }
    }
}

// ---- CSR build: deg -> exclusive scan -> bucket scatter ----
__global__ void k_deg(const int* dst, int* deg, int E) {
    for (int e = blockIdx.x * blockDim.x + threadIdx.x; e < E; e += gridDim.x * blockDim.x)
        atomicAdd(&deg[dst[e]], 1);
}

__global__ void __launch_bounds__(1024) k_scan(const int* deg, int* rowptr, int* cursor, int N) {
    __shared__ int sums[1024];
    int t = threadIdx.x;
    int chunk = (N + 1023) >> 10;
    int lo = t * chunk, hi = min(lo + chunk, N);
    int s = 0;
    for (int i = lo; i < hi; ++i) s += deg[i];
    int val = s;
    sums[t] = val;
    __syncthreads();
    for (int off = 1; off < 1024; off <<= 1) {
        int add = (t >= off) ? sums[t - off] : 0;
        __syncthreads();
        val += add; sums[t] = val;
        __syncthreads();
    }
    int run = val - s;  // exclusive prefix
    for (int i = lo; i < hi; ++i) {
        rowptr[i] = run; cursor[i] = run;
        run += deg[i];
    }
    if (t == 1023) rowptr[N] = run;  // == E
}

__global__ void k_scatter(const int* dst, int* cursor, int* eidx, int E) {
    for (int e = blockIdx.x * blockDim.x + threadIdx.x; e < E; e += gridDim.x * blockDim.x) {
        int pos = atomicAdd(&cursor[dst[e]], 1);
        eidx[pos] = e;
    }
}

// ---- dst-owned aggregation: one wave per node, all sums in registers ----
// Produces v[N][64] = hagg + gat + b_gat, plus BN-e and BN-n stats (block-reduced).
__global__ void __launch_bounds__(256) k_agg(
    P22 in, const int* F, const bf16* NT, const bf16* Meg,
    const float* el, const float* er, const int* rowptr, const int* eidx,
    float* v, float* bn_e_acc, float* bn_n_acc, int N) {
    int lane = threadIdx.x & 63;
    int w = threadIdx.x >> 6;
    int c = lane, h = c >> 5;
    const int* srcp = (const int*)in.p[2];
    float bg = gld(in.p[15], c, F[15]);
    float es = 0.f, eq = 0.f;   // BN-e sums (per col)
    float vs = 0.f, vq = 0.f;   // BN-n sums (per col)

    for (int n = blockIdx.x * 4 + w; n < N; n += gridDim.x * 4) {
        float dn = bf2f(NT[(long)n * 256 + 64 + c]);   // e_dst row of this node
        float errh = er[(long)n * 2 + h];
        int lo = rowptr[n], hi = rowptr[n + 1];
        float ss = 0.f, ssh = 0.f, num = 0.f, den = 0.f;
        auto do_edge = [&](int e) {
            int si = srcp[e];
            const bf16* srow = NT + (long)si * 256;
            float mg  = bf2f(Meg[(long)e * 64 + c]);
            float srv = bf2f(srow[c]);
            float bh  = bf2f(srow[128 + c]);
            float ft  = bf2f(srow[192 + c]);
            float mv = mg + srv + dn;
            float sg = 1.f / (1.f + __expf(-mv));
            ss += sg; ssh += bh * sg;
            es += mv; eq += mv * mv;
            float lg = el[(long)si * 2 + h] + errh;
            lg = lg > 0.f ? lg : 0.2f * lg;
            lg = fminf(fmaxf(lg, -30.f), 30.f);
            float ex = __expf(lg);
            den += ex; num += ft * ex;  // den identical across lanes of a head
        };
        #pragma unroll 2
        for (int j = lo; j < hi; ++j) do_edge(eidx[j]);
        float hagg = ssh / (ss + 1e-6f);
        float gat = den > 0.f ? num / den : 0.f;   // zero in-degree safety
        float vv = hagg + gat + bg;
        v[(long)n * 64 + c] = vv;
        vs += vv; vq += vv * vv;
    }

    __shared__ float r1[256], r2[256];
    r1[threadIdx.x] = es; r2[threadIdx.x] = eq;
    __syncthreads();
    if (threadIdx.x < 64) {
        atomicAdd(bn_e_acc + c,      r1[c] + r1[64 + c] + r1[128 + c] + r1[192 + c]);
        atomicAdd(bn_e_acc + 64 + c, r2[c] + r2[64 + c] + r2[128 + c] + r2[192 + c]);
    }
    __syncthreads();
    r1[threadIdx.x] = vs; r2[threadIdx.x] = vq;
    __syncthreads();
    if (threadIdx.x < 64) {
        atomicAdd(bn_n_acc + c,      r1[c] + r1[64 + c] + r1[128 + c] + r1[192 + c]);
        atomicAdd(bn_n_acc + 64 + c, r2[c] + r2[64 + c] + r2[128 + c] + r2[192 + c]);
    }
}

// ---- x output: x = node + silu(BN_n(v)) ----
__global__ void k_x_out(P22 in, const int* F, const float* v, const float* acc,
                        void* d_out, int N) {
    int f_out = F[0];
    int c = threadIdx.x & 63;
    int slot = threadIdx.x >> 6;
    float inv = 1.f / (float)N;
    float mean = acc[c] * inv;
    float var = fmaxf(acc[64 + c] * inv - mean * mean, 0.f);
    float rstd = rsqrtf(var + 1e-5f);
    float ga = gld(in.p[18], c, F[18]), be = gld(in.p[19], c, F[19]);
    for (int n = blockIdx.x * 4 + slot; n < N; n += gridDim.x * 4) {
        float t = (v[(long)n * 64 + c] - mean) * rstd * ga + be;
        float sl = t / (1.f + __expf(-t));
        float x = fin(gld(in.p[0], (long)n * 64 + c, F[0]) + sl);
        if (f_out) ((float*)d_out)[(long)n * 64 + c] = x;
        else       ((bf16*)d_out)[(long)n * 64 + c] = (bf16)x;
    }
}

// ---- edge output: y = ef + silu(BN_e(m)), pure streaming (no MFMA) ----
__global__ void __launch_bounds__(256) k_edge_y(
    P22 in, const int* F, const bf16* NT, const bf16* Meg,
    const float* bn_e_acc, void* d_out, int N, int E) {
    int f_ef = F[1], f_out = F[0];
    const int* srcp = (const int*)in.p[2];
    const int* dstp = (const int*)in.p[3];
    int tid = blockIdx.x * 256 + threadIdx.x;
    int oc = tid & 7, c0 = oc * 8;        // constant per thread (stride multiple of 8)
    float mean[8], rstd[8], ga[8], be[8];
    float invE = 1.f / (float)E;
    #pragma unroll
    for (int j = 0; j < 8; ++j) {
        int c = c0 + j;
        float mn = bn_e_acc[c] * invE;
        float vr = fmaxf(bn_e_acc[64 + c] * invE - mn * mn, 0.f);
        mean[j] = mn; rstd[j] = rsqrtf(vr + 1e-5f);
        ga[j] = gld(in.p[20], c, F[20]); be[j] = gld(in.p[21], c, F[21]);
    }
    char* yb = (char*)d_out + (size_t)N * 64 * (f_out ? 4 : 2);
    int estride = (gridDim.x * 256) >> 3;
    for (long e = tid >> 3; e < E; e += estride) {
        int si = srcp[e], di = dstp[e];
        bf16x8 mg = *reinterpret_cast<const bf16x8*>(Meg + e * 64 + c0);
        bf16x8 sr = *reinterpret_cast<const bf16x8*>(NT + (long)si * 256 + c0);
        bf16x8 dr = *reinterpret_cast<const bf16x8*>(NT + (long)di * 256 + 64 + c0);
        float ef[8]; ld8f(in.p[1], e * 64 + c0, f_ef, ef);
        float y[8];
        #pragma unroll
        for (int j = 0; j < 8; ++j) {
            float mv = bf2f(mg[j]) + bf2f(sr[j]) + bf2f(dr[j]);
            float t = (mv - mean[j]) * rstd[j] * ga[j] + be[j];
            float sl = t / (1.f + __expf(-t));
            y[j] = fin(ef[j] + sl);
        }
        if (f_out) {
            float* yp = (float*)yb + e * 64 + c0;
            f32x4 y0 = {y[0], y[1], y[2], y[3]}, y1 = {y[4], y[5], y[6], y[7]};
            *(f32x4*)yp = y0; *(f32x4*)(yp + 4) = y1;
        } else {
            bf16x8 yv;
            #pragma unroll
            for (int j = 0; j < 8; ++j) yv[j] = (bf16)y[j];
            *reinterpret_cast<bf16x8*>((bf16*)yb + e * 64 + c0) = yv;
        }
    }
}

extern "C" void kernel_launch(void* const* d_in, const int* in_sizes, int n_in,
                              void* d_out, int out_size, void* d_ws, size_t ws_size,
                              hipStream_t stream) {
    P22 p; I22 sz;
    for (int i = 0; i < 22; ++i) { p.p[i] = d_in[i]; sz.n[i] = in_sizes[i]; }
    const int N = in_sizes[0] / 64;
    const int E = in_sizes[2];

    char* ws = (char*)d_ws;
    size_t off = 0;
    auto alloc = [&](size_t bytes) -> void* {
        void* ptr = ws + off;
        off = (off + bytes + 255) & ~(size_t)255;
        return ptr;
    };
    int*   flags  = (int*)  alloc(22 * 4);
    bf16*  NT     = (bf16*) alloc((size_t)N * 256 * 2);   // [e_src|e_dst|Bh|feat] bf16
    float* el     = (float*)alloc((size_t)N * 2 * 4);
    float* er     = (float*)alloc((size_t)N * 2 * 4);
    bf16*  Wcat   = (bf16*) alloc(64 * 256 * 2);
    float* bcat   = (float*)alloc(256 * 4);
    bf16*  Meg    = (bf16*) alloc((size_t)E * 64 * 2);    // edge GEMM result
    int*   rowptr = (int*)  alloc((size_t)(N + 1) * 4);
    int*   cursor = (int*)  alloc((size_t)N * 4);
    int*   eidx   = (int*)  alloc((size_t)E * 4);
    float* v      = (float*)alloc((size_t)N * 64 * 4);    // pre-BN node values
    char* zbase = ws + off;
    int*   deg      = (int*)  alloc((size_t)N * 4);
    float* bn_e_acc = (float*)alloc(128 * 4);
    float* bn_n_acc = (float*)alloc(128 * 4);
    size_t zbytes = (size_t)((ws + off) - zbase);
    hipMemsetAsync(zbase, 0, zbytes, stream);

    const int* dstp = (const int*)d_in[3];

    hipLaunchKernelGGL(k_detect, dim3(22), dim3(64), 0, stream, p, sz, flags);
    hipLaunchKernelGGL(k_prep, dim3(1), dim3(256), 0, stream, p, flags, Wcat, bcat);
    hipLaunchKernelGGL(k_node_gemm, dim3(800), dim3(256), 0, stream, p, flags, Wcat, bcat, NT, N);
    hipLaunchKernelGGL(k_elr, dim3(512), dim3(256), 0, stream, p, flags, NT, el, er, N);
    hipLaunchKernelGGL(k_edge_gemm, dim3(1024), dim3(256), 0, stream, p, flags, Meg, E);
    hipLaunchKernelGGL(k_deg, dim3(1024), dim3(256), 0, stream, dstp, deg, E);
    hipLaunchKernelGGL(k_scan, dim3(1), dim3(1024), 0, stream, deg, rowptr, cursor, N);
    hipLaunchKernelGGL(k_scatter, dim3(1024), dim3(256), 0, stream, dstp, cursor, eidx, E);
    hipLaunchKernelGGL(k_agg, dim3(2048), dim3(256), 0, stream,
                       p, flags, NT, Meg, el, er, rowptr, eidx, v, bn_e_acc, bn_n_acc, N);
    hipLaunchKernelGGL(k_x_out, dim3(512), dim3(256), 0, stream, p, flags, v, bn_n_acc, d_out, N);
    hipLaunchKernelGGL(k_edge_y, dim3(2048), dim3(256), 0, stream,
                       p, flags, NT, Meg, bn_e_acc, d_out, N, E);
}

// Round 4
// 919.136 us; speedup vs baseline: 1.6872x; 1.0460x over previous
//
#include <hip/hip_runtime.h>
#include <hip/hip_bf16.h>
#include <stdint.h>

typedef __bf16 bf16;
typedef __bf16 bf16x8 __attribute__((ext_vector_type(8)));
typedef float f32x4 __attribute__((ext_vector_type(4)));

struct P22 { const void* p[22]; };
struct I22 { int n[22]; };

__device__ inline float bf2f(bf16 b) { return (float)b; }
__device__ inline float us2f(unsigned short u) {  // bf16 bits -> f32
    union { unsigned int i; float f; } x; x.i = (unsigned int)u << 16; return x.f;
}
__device__ inline unsigned short f2us(bf16 b) {
    union { bf16 b; unsigned short s; } x; x.b = b; return x.s;
}

// flag-dispatched scalar load: tensor may be bf16 (flag=0) or fp32 (flag=1)
__device__ inline float gld(const void* p, long i, int f32) {
    return f32 ? ((const float*)p)[i] : bf2f(((const bf16*)p)[i]);
}
// 8 contiguous elements -> bf16x8 (MFMA operand)
__device__ inline bf16x8 gld8(const void* p, long i, int f32) {
    bf16x8 r;
    if (f32) {
        const float* q = (const float*)p + i;
        f32x4 a = *(const f32x4*)q, b = *(const f32x4*)(q + 4);
        #pragma unroll
        for (int j = 0; j < 4; ++j) { r[j] = (bf16)a[j]; r[4 + j] = (bf16)b[j]; }
    } else {
        r = *reinterpret_cast<const bf16x8*>((const bf16*)p + i);
    }
    return r;
}
// 8 contiguous elements -> float[8], full precision for fp32 inputs
__device__ inline void ld8f(const void* p, long i, int f32, float* o) {
    if (f32) {
        const float* q = (const float*)p + i;
        f32x4 a = *(const f32x4*)q, b = *(const f32x4*)(q + 4);
        #pragma unroll
        for (int j = 0; j < 4; ++j) { o[j] = a[j]; o[4 + j] = b[j]; }
    } else {
        bf16x8 r = *reinterpret_cast<const bf16x8*>((const bf16*)p + i);
        #pragma unroll
        for (int j = 0; j < 8; ++j) o[j] = bf2f(r[j]);
    }
}
__device__ inline float fin(float v) { return isfinite(v) ? v : 0.f; }

// ---- per-tensor dtype detection (unchanged) ----
__global__ void k_detect(P22 in, I22 sz, int* flags) {
    int t = blockIdx.x;
    if (t == 2 || t == 3) { if (threadIdx.x == 0) flags[t] = 0; return; }  // int tensors
    const unsigned short* u = (const unsigned short*)in.p[t];
    int pairs = sz.n[t] >> 1; if (pairs > 256) pairs = 256;
    int lane = threadIdx.x;  // blockDim = 64
    int insane = 0, evenNZ = 0, oddNZ = 0;
    for (int i = lane; i < pairs; i += 64) {
        unsigned short e = u[2 * i], o = u[2 * i + 1];
        int ee = (e >> 7) & 0xFF;
        if (e != 0) { evenNZ++; if (ee > 133 || ee < 108) insane++; }
        if (o != 0) oddNZ++;
    }
    #pragma unroll
    for (int off = 1; off < 64; off <<= 1) {
        insane += __shfl_xor(insane, off, 64);
        evenNZ += __shfl_xor(evenNZ, off, 64);
        oddNZ  += __shfl_xor(oddNZ,  off, 64);
    }
    if (lane == 0) {
        int f32 = 0;
        if (insane * 4 > pairs) f32 = 1;
        else if (evenNZ == 0 && oddNZ > 0) f32 = 1;
        flags[t] = f32;
    }
}

// ---- prep: Wcat = [W_sg | W_dg | W_du | W_su@W_gat] (bf16, 64x256), bcat fp32 ----
__global__ void __launch_bounds__(256) k_prep(P22 in, const int* F, bf16* Wcat, float* bcat) {
    __shared__ float sWsu[64 * 64];
    __shared__ float sWg[64 * 64];
    int tid = threadIdx.x;
    {
        int f1 = F[10], f2 = F[14];
        #pragma unroll 4
        for (int i = tid; i < 4096; i += 256) {
            sWsu[i] = gld(in.p[10], i, f1);
            sWg[i]  = gld(in.p[14], i, f2);
        }
    }
    __syncthreads();
    int j = tid;
    int sec = j >> 6, jc = j & 63;
    if (sec < 3) {
        int wi = sec == 0 ? 4 : (sec == 1 ? 6 : 12);
        const void* W = in.p[wi]; int fW = F[wi];
        #pragma unroll 8
        for (int k = 0; k < 64; ++k) Wcat[k * 256 + j] = (bf16)gld(W, k * 64 + jc, fW);
        bcat[j] = gld(in.p[wi + 1], jc, F[wi + 1]);
    } else {
        #pragma unroll 2
        for (int k = 0; k < 64; ++k) {
            float acc = 0.f;
            #pragma unroll 8
            for (int t = 0; t < 64; ++t) acc += sWsu[k * 64 + t] * sWg[t * 64 + jc];
            Wcat[k * 256 + j] = (bf16)acc;
        }
        float acc = gld(in.p[15], jc, F[15]);  // b_gat
        #pragma unroll 8
        for (int t = 0; t < 64; ++t) acc += gld(in.p[11], t, F[11]) * sWg[t * 64 + jc];
        bcat[j] = acc;
    }
}

// ---- node GEMM: computes [e_src|e_dst|Bh|feat] per node.
// Writes: NT2[N][128] = [e_src|e_dst] (for k_edge_y), PG[N][64] ushort4
// (e_src,e_dst,Bh,feat packed per column, for k_agg single-load gather),
// el/er[N][2] attention dots (k_elr folded in via LDS tile). ----
__global__ void __launch_bounds__(256) k_node_gemm(P22 in, const int* F, const bf16* Wcat,
                                                   const float* bcat, bf16* NT2, ushort4* PG,
                                                   float* el, float* er, int N) {
    __shared__ bf16 tile[16][260];   // +4 pad to break bank patterns
    __shared__ float sal[64], sar[64];
    if (threadIdx.x < 64) sal[threadIdx.x] = gld(in.p[16], threadIdx.x, F[16]);
    else if (threadIdx.x < 128) sar[threadIdx.x - 64] = gld(in.p[17], threadIdx.x - 64, F[17]);

    int f0 = F[0];
    int lane = threadIdx.x & 63;
    int w = threadIdx.x >> 6;
    int col0 = w * 64, q = lane >> 4, li = lane & 15;
    bf16x8 bfr[4][2];
    #pragma unroll
    for (int t = 0; t < 4; ++t)
        #pragma unroll
        for (int h = 0; h < 2; ++h)
            #pragma unroll
            for (int j = 0; j < 8; ++j)
                bfr[t][h][j] = Wcat[(long)(h * 32 + q * 8 + j) * 256 + col0 + t * 16 + li];
    float bias[4];
    #pragma unroll
    for (int t = 0; t < 4; ++t) bias[t] = bcat[col0 + t * 16 + li];

    // PG/el phase mapping (per 16-row tile)
    int prow = threadIdx.x >> 4;          // 0..15
    int pk   = threadIdx.x & 15;          // 0..15
    int pc4  = pk * 4;                    // column group of 4
    int phead = pc4 >> 5;                 // 0 or 1

    int ntiles = (N + 15) >> 4;
    for (int rt = blockIdx.x; rt < ntiles; rt += gridDim.x) {
        int row0 = rt * 16;
        int rload = min(row0 + li, N - 1);
        bf16x8 a0 = gld8(in.p[0], (long)rload * 64 + (q << 3), f0);
        bf16x8 a1 = gld8(in.p[0], (long)rload * 64 + 32 + (q << 3), f0);
        #pragma unroll
        for (int t = 0; t < 4; ++t) {
            f32x4 acc = {0.f, 0.f, 0.f, 0.f};
            acc = __builtin_amdgcn_mfma_f32_16x16x32_bf16(a0, bfr[t][0], acc, 0, 0, 0);
            acc = __builtin_amdgcn_mfma_f32_16x16x32_bf16(a1, bfr[t][1], acc, 0, 0, 0);
            int col = col0 + t * 16 + li;
            #pragma unroll
            for (int r = 0; r < 4; ++r) {
                int rr = q * 4 + r;
                bf16 bv = (bf16)(acc[r] + bias[t]);
                tile[rr][col] = bv;
                if (w < 2 && row0 + rr < N) NT2[(long)(row0 + rr) * 128 + col] = bv;
            }
        }
        __syncthreads();
        // PG pack: one ushort4 per (row,col)
        int grow = row0 + prow;
        if (grow < N) {
            #pragma unroll
            for (int j = 0; j < 4; ++j) {
                int c = pc4 + j;
                ushort4 pv;
                pv.x = f2us(tile[prow][c]);
                pv.y = f2us(tile[prow][64 + c]);
                pv.z = f2us(tile[prow][128 + c]);
                pv.w = f2us(tile[prow][192 + c]);
                PG[(long)grow * 64 + c] = pv;
            }
        }
        // el/er: dot(feat, attn) per head, 8-lane groups
        float pl = 0.f, pr = 0.f;
        #pragma unroll
        for (int j = 0; j < 4; ++j) {
            float f = bf2f(tile[prow][192 + pc4 + j]);
            pl += f * sal[pc4 + j];
            pr += f * sar[pc4 + j];
        }
        pl += __shfl_xor(pl, 1, 64); pr += __shfl_xor(pr, 1, 64);
        pl += __shfl_xor(pl, 2, 64); pr += __shfl_xor(pr, 2, 64);
        pl += __shfl_xor(pl, 4, 64); pr += __shfl_xor(pr, 4, 64);
        if ((pk & 7) == 0 && grow < N) {
            el[(long)grow * 2 + phead] = pl;
            er[(long)grow * 2 + phead] = pr;
        }
        __syncthreads();
    }
}

// ---- edge GEMM: Meg[E][64] = edge_feats @ W_eg + b_eg; also counts deg (k_deg folded) ----
__global__ void __launch_bounds__(256) k_edge_gemm(P22 in, const int* F, bf16* Meg,
                                                   int* deg, int E) {
    int f_ef = F[1];
    int lane = threadIdx.x & 63;
    int w = threadIdx.x >> 6;
    int q = lane >> 4, li = lane & 15;
    const int* dstp = (const int*)in.p[3];
    bf16x8 bfrag[4][2];
    #pragma unroll
    for (int t = 0; t < 4; ++t)
        #pragma unroll
        for (int h = 0; h < 2; ++h)
            #pragma unroll
            for (int j = 0; j < 8; ++j)
                bfrag[t][h][j] = (bf16)gld(in.p[8], (long)(h * 32 + q * 8 + j) * 64 + t * 16 + li, F[8]);
    float bias[4];
    #pragma unroll
    for (int t = 0; t < 4; ++t) bias[t] = gld(in.p[9], t * 16 + li, F[9]);

    int ntiles = E >> 4;   // E divisible by 16
    for (int et = blockIdx.x * 4 + w; et < ntiles; et += gridDim.x * 4) {
        int e0 = et * 16;
        bf16x8 a0 = gld8(in.p[1], (long)(e0 + li) * 64 + (q << 3), f_ef);
        bf16x8 a1 = gld8(in.p[1], (long)(e0 + li) * 64 + 32 + (q << 3), f_ef);
        if (lane < 16) atomicAdd(&deg[dstp[e0 + lane]], 1);
        #pragma unroll
        for (int t = 0; t < 4; ++t) {
            f32x4 c = {0.f, 0.f, 0.f, 0.f};
            c = __builtin_amdgcn_mfma_f32_16x16x32_bf16(a0, bfrag[t][0], c, 0, 0, 0);
            c = __builtin_amdgcn_mfma_f32_16x16x32_bf16(a1, bfrag[t][1], c, 0, 0, 0);
            #pragma unroll
            for (int r = 0; r < 4; ++r) {
                int row = e0 + q * 4 + r;
                Meg[(long)row * 64 + t * 16 + li] = (bf16)(c[r] + bias[t]);
            }
        }
    }
}

// ---- CSR scan ----
__global__ void __launch_bounds__(1024) k_scan(const int* deg, int* rowptr, int* cursor, int N) {
    __shared__ int sums[1024];
    int t = threadIdx.x;
    int chunk = (N + 1023) >> 10;
    int lo = t * chunk, hi = min(lo + chunk, N);
    int s = 0;
    for (int i = lo; i < hi; ++i) s += deg[i];
    int val = s;
    sums[t] = val;
    __syncthreads();
    for (int off = 1; off < 1024; off <<= 1) {
        int add = (t >= off) ? sums[t - off] : 0;
        __syncthreads();
        val += add; sums[t] = val;
        __syncthreads();
    }
    int run = val - s;  // exclusive prefix
    for (int i = lo; i < hi; ++i) {
        rowptr[i] = run; cursor[i] = run;
        run += deg[i];
    }
    if (t == 1023) rowptr[N] = run;  // == E
}

// ---- scatter: ES[pos] = {e, src[e]} so k_agg's key loads are sequential ----
__global__ void k_scatter(const int* src, const int* dst, int* cursor, int2* ES, int E) {
    for (int e = blockIdx.x * blockDim.x + threadIdx.x; e < E; e += gridDim.x * blockDim.x) {
        int pos = atomicAdd(&cursor[dst[e]], 1);
        int2 v; v.x = e; v.y = src[e];
        ES[pos] = v;
    }
}

// ---- dst-owned aggregation: one wave per node, register accumulators.
// Dependent-load chain is now depth-1: ES[j] sequential -> {PG, Meg, el} gathers. ----
__global__ void __launch_bounds__(256) k_agg(
    P22 in, const int* F, const ushort4* PG, const bf16* Meg,
    const float* el, const float* er, const int* rowptr, const int2* ES,
    float* v, float* bn_e_acc, float* bn_n_acc, int N) {
    int lane = threadIdx.x & 63;
    int w = threadIdx.x >> 6;
    int c = lane, h = c >> 5;
    float bg = gld(in.p[15], c, F[15]);
    float es_ = 0.f, eq = 0.f;  // BN-e sums (per col)
    float vs = 0.f, vq = 0.f;   // BN-n sums (per col)

    for (int n = blockIdx.x * 4 + w; n < N; n += gridDim.x * 4) {
        float dn = us2f(PG[(long)n * 64 + c].y);      // e_dst value of this node
        float errh = er[(long)n * 2 + h];
        int lo = rowptr[n], hi = rowptr[n + 1];
        float ss = 0.f, ssh = 0.f, num = 0.f, den = 0.f;
        #pragma unroll 4
        for (int j = lo; j < hi; ++j) {
            int2 e2 = ES[j];                           // sequential, wave-uniform
            ushort4 g = PG[(long)e2.y * 64 + c];       // one 8B gather
            float mg = bf2f(Meg[(long)e2.x * 64 + c]); // one 2B gather (128B/wave)
            float srv = us2f(g.x), bh = us2f(g.z), ft = us2f(g.w);
            float mv = mg + srv + dn;
            float sg = 1.f / (1.f + __expf(-mv));
            ss += sg; ssh += bh * sg;
            es_ += mv; eq += mv * mv;
            float lg = el[(long)e2.y * 2 + h] + errh;
            lg = lg > 0.f ? lg : 0.2f * lg;
            lg = fminf(fmaxf(lg, -30.f), 30.f);
            float ex = __expf(lg);
            den += ex; num += ft * ex;
        }
        float hagg = ssh / (ss + 1e-6f);
        float gat = den > 0.f ? num / den : 0.f;
        float vv = hagg + gat + bg;
        v[(long)n * 64 + c] = vv;
        vs += vv; vq += vv * vv;
    }

    __shared__ float r1[256], r2[256];
    r1[threadIdx.x] = es_; r2[threadIdx.x] = eq;
    __syncthreads();
    if (threadIdx.x < 64) {
        atomicAdd(bn_e_acc + c,      r1[c] + r1[64 + c] + r1[128 + c] + r1[192 + c]);
        atomicAdd(bn_e_acc + 64 + c, r2[c] + r2[64 + c] + r2[128 + c] + r2[192 + c]);
    }
    __syncthreads();
    r1[threadIdx.x] = vs; r2[threadIdx.x] = vq;
    __syncthreads();
    if (threadIdx.x < 64) {
        atomicAdd(bn_n_acc + c,      r1[c] + r1[64 + c] + r1[128 + c] + r1[192 + c]);
        atomicAdd(bn_n_acc + 64 + c, r2[c] + r2[64 + c] + r2[128 + c] + r2[192 + c]);
    }
}

// ---- x output: x = node + silu(BN_n(v)) ----
__global__ void k_x_out(P22 in, const int* F, const float* v, const float* acc,
                        void* d_out, int N) {
    int f_out = F[0];
    int c = threadIdx.x & 63;
    int slot = threadIdx.x >> 6;
    float inv = 1.f / (float)N;
    float mean = acc[c] * inv;
    float var = fmaxf(acc[64 + c] * inv - mean * mean, 0.f);
    float rstd = rsqrtf(var + 1e-5f);
    float ga = gld(in.p[18], c, F[18]), be = gld(in.p[19], c, F[19]);
    for (int n = blockIdx.x * 4 + slot; n < N; n += gridDim.x * 4) {
        float t = (v[(long)n * 64 + c] - mean) * rstd * ga + be;
        float sl = t / (1.f + __expf(-t));
        float x = fin(gld(in.p[0], (long)n * 64 + c, F[0]) + sl);
        if (f_out) ((float*)d_out)[(long)n * 64 + c] = x;
        else       ((bf16*)d_out)[(long)n * 64 + c] = (bf16)x;
    }
}

// ---- edge output: y = ef + silu(BN_e(m)), pure streaming ----
__global__ void __launch_bounds__(256) k_edge_y(
    P22 in, const int* F, const bf16* NT2, const bf16* Meg,
    const float* bn_e_acc, void* d_out, int N, int E) {
    int f_ef = F[1], f_out = F[0];
    const int* srcp = (const int*)in.p[2];
    const int* dstp = (const int*)in.p[3];
    int tid = blockIdx.x * 256 + threadIdx.x;
    int oc = tid & 7, c0 = oc * 8;
    float mean[8], rstd[8], ga[8], be[8];
    float invE = 1.f / (float)E;
    #pragma unroll
    for (int j = 0; j < 8; ++j) {
        int c = c0 + j;
        float mn = bn_e_acc[c] * invE;
        float vr = fmaxf(bn_e_acc[64 + c] * invE - mn * mn, 0.f);
        mean[j] = mn; rstd[j] = rsqrtf(vr + 1e-5f);
        ga[j] = gld(in.p[20], c, F[20]); be[j] = gld(in.p[21], c, F[21]);
    }
    char* yb = (char*)d_out + (size_t)N * 64 * (f_out ? 4 : 2);
    int estride = (gridDim.x * 256) >> 3;
    for (long e = tid >> 3; e < E; e += estride) {
        int si = srcp[e], di = dstp[e];
        bf16x8 mg = *reinterpret_cast<const bf16x8*>(Meg + e * 64 + c0);
        bf16x8 sr = *reinterpret_cast<const bf16x8*>(NT2 + (long)si * 128 + c0);
        bf16x8 dr = *reinterpret_cast<const bf16x8*>(NT2 + (long)di * 128 + 64 + c0);
        float ef[8]; ld8f(in.p[1], e * 64 + c0, f_ef, ef);
        float y[8];
        #pragma unroll
        for (int j = 0; j < 8; ++j) {
            float mv = bf2f(mg[j]) + bf2f(sr[j]) + bf2f(dr[j]);
            float t = (mv - mean[j]) * rstd[j] * ga[j] + be[j];
            float sl = t / (1.f + __expf(-t));
            y[j] = fin(ef[j] + sl);
        }
        if (f_out) {
            float* yp = (float*)yb + e * 64 + c0;
            f32x4 y0 = {y[0], y[1], y[2], y[3]}, y1 = {y[4], y[5], y[6], y[7]};
            *(f32x4*)yp = y0; *(f32x4*)(yp + 4) = y1;
        } else {
            bf16x8 yv;
            #pragma unroll
            for (int j = 0; j < 8; ++j) yv[j] = (bf16)y[j];
            *reinterpret_cast<bf16x8*>((bf16*)yb + e * 64 + c0) = yv;
        }
    }
}

extern "C" void kernel_launch(void* const* d_in, const int* in_sizes, int n_in,
                              void* d_out, int out_size, void* d_ws, size_t ws_size,
                              hipStream_t stream) {
    P22 p; I22 sz;
    for (int i = 0; i < 22; ++i) { p.p[i] = d_in[i]; sz.n[i] = in_sizes[i]; }
    const int N = in_sizes[0] / 64;
    const int E = in_sizes[2];

    char* ws = (char*)d_ws;
    size_t off = 0;
    auto alloc = [&](size_t bytes) -> void* {
        void* ptr = ws + off;
        off = (off + bytes + 255) & ~(size_t)255;
        return ptr;
    };
    int*   flags  = (int*)    alloc(22 * 4);
    bf16*  NT2    = (bf16*)   alloc((size_t)N * 128 * 2);   // [e_src|e_dst] bf16
    ushort4* PG   = (ushort4*)alloc((size_t)N * 64 * 8);    // packed per-col gather data
    float* el     = (float*)  alloc((size_t)N * 2 * 4);
    float* er     = (float*)  alloc((size_t)N * 2 * 4);
    bf16*  Wcat   = (bf16*)   alloc(64 * 256 * 2);
    float* bcat   = (float*)  alloc(256 * 4);
    bf16*  Meg    = (bf16*)   alloc((size_t)E * 64 * 2);    // edge GEMM result
    int*   rowptr = (int*)    alloc((size_t)(N + 1) * 4);
    int*   cursor = (int*)    alloc((size_t)N * 4);
    int2*  ES     = (int2*)   alloc((size_t)E * 8);         // dst-sorted {e, src}
    float* v      = (float*)  alloc((size_t)N * 64 * 4);    // pre-BN node values
    char* zbase = ws + off;
    int*   deg      = (int*)  alloc((size_t)N * 4);
    float* bn_e_acc = (float*)alloc(128 * 4);
    float* bn_n_acc = (float*)alloc(128 * 4);
    size_t zbytes = (size_t)((ws + off) - zbase);
    hipMemsetAsync(zbase, 0, zbytes, stream);

    const int* srcp = (const int*)d_in[2];
    const int* dstp = (const int*)d_in[3];

    hipLaunchKernelGGL(k_detect, dim3(22), dim3(64), 0, stream, p, sz, flags);
    hipLaunchKernelGGL(k_prep, dim3(1), dim3(256), 0, stream, p, flags, Wcat, bcat);
    hipLaunchKernelGGL(k_node_gemm, dim3(800), dim3(256), 0, stream,
                       p, flags, Wcat, bcat, NT2, PG, el, er, N);
    hipLaunchKernelGGL(k_edge_gemm, dim3(1024), dim3(256), 0, stream, p, flags, Meg, deg, E);
    hipLaunchKernelGGL(k_scan, dim3(1), dim3(1024), 0, stream, deg, rowptr, cursor, N);
    hipLaunchKernelGGL(k_scatter, dim3(1024), dim3(256), 0, stream, srcp, dstp, cursor, ES, E);
    hipLaunchKernelGGL(k_agg, dim3(2048), dim3(256), 0, stream,
                       p, flags, PG, Meg, el, er, rowptr, ES, v, bn_e_acc, bn_n_acc, N);
    hipLaunchKernelGGL(k_x_out, dim3(512), dim3(256), 0, stream, p, flags, v, bn_n_acc, d_out, N);
    hipLaunchKernelGGL(k_edge_y, dim3(2048), dim3(256), 0, stream,
                       p, flags, NT2, Meg, bn_e_acc, d_out, N, E);
}

// Round 5
// 896.463 us; speedup vs baseline: 1.7299x; 1.0253x over previous
//
#include <hip/hip_runtime.h>
#include <hip/hip_bf16.h>
#include <stdint.h>

typedef __bf16 bf16;
typedef __bf16 bf16x8 __attribute__((ext_vector_type(8)));
typedef float f32x4 __attribute__((ext_vector_type(4)));

struct P22 { const void* p[22]; };
struct I22 { int n[22]; };

__device__ inline float bf2f(bf16 b) { return (float)b; }
__device__ inline float us2f(unsigned short u) {  // bf16 bits -> f32
    union { unsigned int i; float f; } x; x.i = (unsigned int)u << 16; return x.f;
}
__device__ inline unsigned short f2us(bf16 b) {
    union { bf16 b; unsigned short s; } x; x.b = b; return x.s;
}

// flag-dispatched scalar load: tensor may be bf16 (flag=0) or fp32 (flag=1)
__device__ inline float gld(const void* p, long i, int f32) {
    return f32 ? ((const float*)p)[i] : bf2f(((const bf16*)p)[i]);
}
// 8 contiguous elements -> bf16x8 (MFMA operand)
__device__ inline bf16x8 gld8(const void* p, long i, int f32) {
    bf16x8 r;
    if (f32) {
        const float* q = (const float*)p + i;
        f32x4 a = *(const f32x4*)q, b = *(const f32x4*)(q + 4);
        #pragma unroll
        for (int j = 0; j < 4; ++j) { r[j] = (bf16)a[j]; r[4 + j] = (bf16)b[j]; }
    } else {
        r = *reinterpret_cast<const bf16x8*>((const bf16*)p + i);
    }
    return r;
}
// 8 contiguous elements -> float[8], full precision for fp32 inputs
__device__ inline void ld8f(const void* p, long i, int f32, float* o) {
    if (f32) {
        const float* q = (const float*)p + i;
        f32x4 a = *(const f32x4*)q, b = *(const f32x4*)(q + 4);
        #pragma unroll
        for (int j = 0; j < 4; ++j) { o[j] = a[j]; o[4 + j] = b[j]; }
    } else {
        bf16x8 r = *reinterpret_cast<const bf16x8*>((const bf16*)p + i);
        #pragma unroll
        for (int j = 0; j < 8; ++j) o[j] = bf2f(r[j]);
    }
}
__device__ inline float fin(float v) { return isfinite(v) ? v : 0.f; }

// ---- per-tensor dtype detection (unchanged) ----
__global__ void k_detect(P22 in, I22 sz, int* flags) {
    int t = blockIdx.x;
    if (t == 2 || t == 3) { if (threadIdx.x == 0) flags[t] = 0; return; }  // int tensors
    const unsigned short* u = (const unsigned short*)in.p[t];
    int pairs = sz.n[t] >> 1; if (pairs > 256) pairs = 256;
    int lane = threadIdx.x;  // blockDim = 64
    int insane = 0, evenNZ = 0, oddNZ = 0;
    for (int i = lane; i < pairs; i += 64) {
        unsigned short e = u[2 * i], o = u[2 * i + 1];
        int ee = (e >> 7) & 0xFF;
        if (e != 0) { evenNZ++; if (ee > 133 || ee < 108) insane++; }
        if (o != 0) oddNZ++;
    }
    #pragma unroll
    for (int off = 1; off < 64; off <<= 1) {
        insane += __shfl_xor(insane, off, 64);
        evenNZ += __shfl_xor(evenNZ, off, 64);
        oddNZ  += __shfl_xor(oddNZ,  off, 64);
    }
    if (lane == 0) {
        int f32 = 0;
        if (insane * 4 > pairs) f32 = 1;
        else if (evenNZ == 0 && oddNZ > 0) f32 = 1;
        flags[t] = f32;
    }
}

// ---- prep: Wcat = [W_sg | W_dg | W_du | W_su@W_gat] (bf16, 64x256), bcat fp32 ----
__global__ void __launch_bounds__(256) k_prep(P22 in, const int* F, bf16* Wcat, float* bcat) {
    __shared__ float sWsu[64 * 64];
    __shared__ float sWg[64 * 64];
    int tid = threadIdx.x;
    {
        int f1 = F[10], f2 = F[14];
        #pragma unroll 4
        for (int i = tid; i < 4096; i += 256) {
            sWsu[i] = gld(in.p[10], i, f1);
            sWg[i]  = gld(in.p[14], i, f2);
        }
    }
    __syncthreads();
    int j = tid;
    int sec = j >> 6, jc = j & 63;
    if (sec < 3) {
        int wi = sec == 0 ? 4 : (sec == 1 ? 6 : 12);
        const void* W = in.p[wi]; int fW = F[wi];
        #pragma unroll 8
        for (int k = 0; k < 64; ++k) Wcat[k * 256 + j] = (bf16)gld(W, k * 64 + jc, fW);
        bcat[j] = gld(in.p[wi + 1], jc, F[wi + 1]);
    } else {
        #pragma unroll 2
        for (int k = 0; k < 64; ++k) {
            float acc = 0.f;
            #pragma unroll 8
            for (int t = 0; t < 64; ++t) acc += sWsu[k * 64 + t] * sWg[t * 64 + jc];
            Wcat[k * 256 + j] = (bf16)acc;
        }
        float acc = gld(in.p[15], jc, F[15]);  // b_gat
        #pragma unroll 8
        for (int t = 0; t < 64; ++t) acc += gld(in.p[11], t, F[11]) * sWg[t * 64 + jc];
        bcat[j] = acc;
    }
}

// ---- node GEMM: computes [e_src|e_dst|Bh|feat] per node.
// Writes: ESRC[N][64], EDST[N][64] bf16 (gathered by k_edge_gemm),
// PG2[N][64] ushort2 = (Bh, feat) (gathered by k_agg), el/er[N][2]. ----
__global__ void __launch_bounds__(256) k_node_gemm(P22 in, const int* F, const bf16* Wcat,
                                                   const float* bcat, bf16* ESRC, bf16* EDST,
                                                   ushort2* PG2, float* el, float* er, int N) {
    __shared__ bf16 tile[16][260];   // +4 pad to break bank patterns
    __shared__ float sal[64], sar[64];
    if (threadIdx.x < 64) sal[threadIdx.x] = gld(in.p[16], threadIdx.x, F[16]);
    else if (threadIdx.x < 128) sar[threadIdx.x - 64] = gld(in.p[17], threadIdx.x - 64, F[17]);

    int f0 = F[0];
    int lane = threadIdx.x & 63;
    int w = threadIdx.x >> 6;
    int col0 = w * 64, q = lane >> 4, li = lane & 15;
    bf16x8 bfr[4][2];
    #pragma unroll
    for (int t = 0; t < 4; ++t)
        #pragma unroll
        for (int h = 0; h < 2; ++h)
            #pragma unroll
            for (int j = 0; j < 8; ++j)
                bfr[t][h][j] = Wcat[(long)(h * 32 + q * 8 + j) * 256 + col0 + t * 16 + li];
    float bias[4];
    #pragma unroll
    for (int t = 0; t < 4; ++t) bias[t] = bcat[col0 + t * 16 + li];

    // PG2/el phase mapping (per 16-row tile)
    int prow = threadIdx.x >> 4;          // 0..15
    int pk   = threadIdx.x & 15;          // 0..15
    int pc4  = pk * 4;                    // column group of 4
    int phead = pc4 >> 5;                 // 0 or 1

    int ntiles = (N + 15) >> 4;
    for (int rt = blockIdx.x; rt < ntiles; rt += gridDim.x) {
        int row0 = rt * 16;
        int rload = min(row0 + li, N - 1);
        bf16x8 a0 = gld8(in.p[0], (long)rload * 64 + (q << 3), f0);
        bf16x8 a1 = gld8(in.p[0], (long)rload * 64 + 32 + (q << 3), f0);
        #pragma unroll
        for (int t = 0; t < 4; ++t) {
            f32x4 acc = {0.f, 0.f, 0.f, 0.f};
            acc = __builtin_amdgcn_mfma_f32_16x16x32_bf16(a0, bfr[t][0], acc, 0, 0, 0);
            acc = __builtin_amdgcn_mfma_f32_16x16x32_bf16(a1, bfr[t][1], acc, 0, 0, 0);
            int col = col0 + t * 16 + li;
            #pragma unroll
            for (int r = 0; r < 4; ++r) {
                int rr = q * 4 + r;
                bf16 bv = (bf16)(acc[r] + bias[t]);
                tile[rr][col] = bv;
                int row = row0 + rr;
                if (row < N) {
                    if (w == 0)      ESRC[(long)row * 64 + col] = bv;
                    else if (w == 1) EDST[(long)row * 64 + (col - 64)] = bv;
                }
            }
        }
        __syncthreads();
        // PG2 pack: (Bh, feat) per (row,col)
        int grow = row0 + prow;
        if (grow < N) {
            #pragma unroll
            for (int j = 0; j < 4; ++j) {
                int c = pc4 + j;
                ushort2 pv;
                pv.x = f2us(tile[prow][128 + c]);
                pv.y = f2us(tile[prow][192 + c]);
                PG2[(long)grow * 64 + c] = pv;
            }
        }
        // el/er: dot(feat, attn) per head, 8-lane groups
        float pl = 0.f, pr = 0.f;
        #pragma unroll
        for (int j = 0; j < 4; ++j) {
            float f = bf2f(tile[prow][192 + pc4 + j]);
            pl += f * sal[pc4 + j];
            pr += f * sar[pc4 + j];
        }
        pl += __shfl_xor(pl, 1, 64); pr += __shfl_xor(pr, 1, 64);
        pl += __shfl_xor(pl, 2, 64); pr += __shfl_xor(pr, 2, 64);
        pl += __shfl_xor(pl, 4, 64); pr += __shfl_xor(pr, 4, 64);
        if ((pk & 7) == 0 && grow < N) {
            el[(long)grow * 2 + phead] = pl;
            er[(long)grow * 2 + phead] = pr;
        }
        __syncthreads();
    }
}

// ---- edge GEMM + gather + stats: M[E][64] = full m = ef@W_eg + b + e_src[si] + e_dst[di]
// (bf16), BN-e sum/sumsq accumulated from fp32 values, deg counted. ----
__global__ void __launch_bounds__(256) k_edge_gemm(
    P22 in, const int* F, const bf16* ESRC, const bf16* EDST,
    bf16* M, int* deg, float* bn_e_acc, int E) {
    int f_ef = F[1];
    int lane = threadIdx.x & 63;
    int w = threadIdx.x >> 6;
    int q = lane >> 4, li = lane & 15;
    const int* srcp = (const int*)in.p[2];
    const int* dstp = (const int*)in.p[3];
    bf16x8 bfrag[4][2];
    #pragma unroll
    for (int t = 0; t < 4; ++t)
        #pragma unroll
        for (int h = 0; h < 2; ++h)
            #pragma unroll
            for (int j = 0; j < 8; ++j)
                bfrag[t][h][j] = (bf16)gld(in.p[8], (long)(h * 32 + q * 8 + j) * 64 + t * 16 + li, F[8]);
    float bias[4];
    #pragma unroll
    for (int t = 0; t < 4; ++t) bias[t] = gld(in.p[9], t * 16 + li, F[9]);

    float es[4] = {0.f, 0.f, 0.f, 0.f}, eq[4] = {0.f, 0.f, 0.f, 0.f};

    int ntiles = E >> 4;   // E divisible by 16
    for (int et = blockIdx.x * 4 + w; et < ntiles; et += gridDim.x * 4) {
        int e0 = et * 16;
        bf16x8 a0 = gld8(in.p[1], (long)(e0 + li) * 64 + (q << 3), f_ef);
        bf16x8 a1 = gld8(in.p[1], (long)(e0 + li) * 64 + 32 + (q << 3), f_ef);
        if (lane < 16) atomicAdd(&deg[dstp[e0 + lane]], 1);
        // src/dst gathers for this q-group's 4 rows
        int si[4], di[4];
        #pragma unroll
        for (int r = 0; r < 4; ++r) {
            int row = e0 + q * 4 + r;
            si[r] = srcp[row]; di[r] = dstp[row];
        }
        bf16 sv[4][4], dv[4][4];
        #pragma unroll
        for (int r = 0; r < 4; ++r)
            #pragma unroll
            for (int t = 0; t < 4; ++t) {
                sv[r][t] = ESRC[(long)si[r] * 64 + t * 16 + li];
                dv[r][t] = EDST[(long)di[r] * 64 + t * 16 + li];
            }
        f32x4 acc[4];
        #pragma unroll
        for (int t = 0; t < 4; ++t) {
            f32x4 c = {0.f, 0.f, 0.f, 0.f};
            c = __builtin_amdgcn_mfma_f32_16x16x32_bf16(a0, bfrag[t][0], c, 0, 0, 0);
            c = __builtin_amdgcn_mfma_f32_16x16x32_bf16(a1, bfrag[t][1], c, 0, 0, 0);
            acc[t] = c;
        }
        #pragma unroll
        for (int r = 0; r < 4; ++r) {
            int row = e0 + q * 4 + r;
            #pragma unroll
            for (int t = 0; t < 4; ++t) {
                float mval = acc[t][r] + bias[t] + bf2f(sv[r][t]) + bf2f(dv[r][t]);
                M[(long)row * 64 + t * 16 + li] = (bf16)mval;
                es[t] += mval; eq[t] += mval * mval;
            }
        }
    }
    __shared__ float red_s[256], red_q[256];
    #pragma unroll
    for (int t = 0; t < 4; ++t) {
        float s = es[t], qq = eq[t];
        s += __shfl_xor(s, 16, 64); s += __shfl_xor(s, 32, 64);
        qq += __shfl_xor(qq, 16, 64); qq += __shfl_xor(qq, 32, 64);
        if (q == 0) { red_s[w * 64 + t * 16 + li] = s; red_q[w * 64 + t * 16 + li] = qq; }
    }
    __syncthreads();
    if (threadIdx.x < 64) {
        int c = threadIdx.x;
        float s  = red_s[c] + red_s[64 + c] + red_s[128 + c] + red_s[192 + c];
        float qq = red_q[c] + red_q[64 + c] + red_q[128 + c] + red_q[192 + c];
        atomicAdd(bn_e_acc + c, s);
        atomicAdd(bn_e_acc + 64 + c, qq);
    }
}

// ---- CSR scan ----
__global__ void __launch_bounds__(1024) k_scan(const int* deg, int* rowptr, int* cursor, int N) {
    __shared__ int sums[1024];
    int t = threadIdx.x;
    int chunk = (N + 1023) >> 10;
    int lo = t * chunk, hi = min(lo + chunk, N);
    int s = 0;
    for (int i = lo; i < hi; ++i) s += deg[i];
    int val = s;
    sums[t] = val;
    __syncthreads();
    for (int off = 1; off < 1024; off <<= 1) {
        int add = (t >= off) ? sums[t - off] : 0;
        __syncthreads();
        val += add; sums[t] = val;
        __syncthreads();
    }
    int run = val - s;  // exclusive prefix
    for (int i = lo; i < hi; ++i) {
        rowptr[i] = run; cursor[i] = run;
        run += deg[i];
    }
    if (t == 1023) rowptr[N] = run;  // == E
}

// ---- scatter: ES[pos] = {e, src[e]} so k_agg's key loads are sequential ----
__global__ void k_scatter(const int* src, const int* dst, int* cursor, int2* ES, int E) {
    for (int e = blockIdx.x * blockDim.x + threadIdx.x; e < E; e += gridDim.x * blockDim.x) {
        int pos = atomicAdd(&cursor[dst[e]], 1);
        int2 v; v.x = e; v.y = src[e];
        ES[pos] = v;
    }
}

// ---- dst-owned aggregation: one wave per node, register accumulators.
// Slimmed: per edge = ES (seq) + PG2 4B gather + M 2B gather + el; sigmoid on m. ----
__global__ void __launch_bounds__(256) k_agg(
    P22 in, const int* F, const ushort2* PG2, const bf16* M,
    const float* el, const float* er, const int* rowptr, const int2* ES,
    float* v, float* bn_n_acc, int N) {
    int lane = threadIdx.x & 63;
    int w = threadIdx.x >> 6;
    int c = lane, h = c >> 5;
    float bg = gld(in.p[15], c, F[15]);
    float vs = 0.f, vq = 0.f;   // BN-n sums (per col)

    for (int n = blockIdx.x * 4 + w; n < N; n += gridDim.x * 4) {
        float errh = er[(long)n * 2 + h];
        int lo = rowptr[n], hi = rowptr[n + 1];
        float ss = 0.f, ssh = 0.f, num = 0.f, den = 0.f;
        #pragma unroll 4
        for (int j = lo; j < hi; ++j) {
            int2 e2 = ES[j];                           // sequential, wave-uniform
            ushort2 g = PG2[(long)e2.y * 64 + c];      // one 4B gather (Bh, feat)
            float mv = bf2f(M[(long)e2.x * 64 + c]);   // one 2B gather (coalesced 128B/wave)
            float sg = 1.f / (1.f + __expf(-mv));
            ss += sg; ssh += us2f(g.x) * sg;
            float lg = el[(long)e2.y * 2 + h] + errh;
            lg = lg > 0.f ? lg : 0.2f * lg;
            lg = fminf(fmaxf(lg, -30.f), 30.f);
            float ex = __expf(lg);
            den += ex; num += us2f(g.y) * ex;
        }
        float hagg = ssh / (ss + 1e-6f);
        float gat = den > 0.f ? num / den : 0.f;
        float vv = hagg + gat + bg;
        v[(long)n * 64 + c] = vv;
        vs += vv; vq += vv * vv;
    }

    __shared__ float r1[256], r2[256];
    r1[threadIdx.x] = vs; r2[threadIdx.x] = vq;
    __syncthreads();
    if (threadIdx.x < 64) {
        atomicAdd(bn_n_acc + c,      r1[c] + r1[64 + c] + r1[128 + c] + r1[192 + c]);
        atomicAdd(bn_n_acc + 64 + c, r2[c] + r2[64 + c] + r2[128 + c] + r2[192 + c]);
    }
}

// ---- x output: x = node + silu(BN_n(v)) ----
__global__ void k_x_out(P22 in, const int* F, const float* v, const float* acc,
                        void* d_out, int N) {
    int f_out = F[0];
    int c = threadIdx.x & 63;
    int slot = threadIdx.x >> 6;
    float inv = 1.f / (float)N;
    float mean = acc[c] * inv;
    float var = fmaxf(acc[64 + c] * inv - mean * mean, 0.f);
    float rstd = rsqrtf(var + 1e-5f);
    float ga = gld(in.p[18], c, F[18]), be = gld(in.p[19], c, F[19]);
    for (int n = blockIdx.x * 4 + slot; n < N; n += gridDim.x * 4) {
        float t = (v[(long)n * 64 + c] - mean) * rstd * ga + be;
        float sl = t / (1.f + __expf(-t));
        float x = fin(gld(in.p[0], (long)n * 64 + c, F[0]) + sl);
        if (f_out) ((float*)d_out)[(long)n * 64 + c] = x;
        else       ((bf16*)d_out)[(long)n * 64 + c] = (bf16)x;
    }
}

// ---- edge output: y = ef + silu(BN_e(m)), pure contiguous streaming (no gathers) ----
__global__ void __launch_bounds__(256) k_edge_y(
    P22 in, const int* F, const bf16* M, const float* bn_e_acc,
    void* d_out, int N, int E) {
    int f_ef = F[1], f_out = F[0];
    int tid = blockIdx.x * 256 + threadIdx.x;
    int oc = tid & 7, c0 = oc * 8;
    float mean[8], rstd[8], ga[8], be[8];
    float invE = 1.f / (float)E;
    #pragma unroll
    for (int j = 0; j < 8; ++j) {
        int c = c0 + j;
        float mn = bn_e_acc[c] * invE;
        float vr = fmaxf(bn_e_acc[64 + c] * invE - mn * mn, 0.f);
        mean[j] = mn; rstd[j] = rsqrtf(vr + 1e-5f);
        ga[j] = gld(in.p[20], c, F[20]); be[j] = gld(in.p[21], c, F[21]);
    }
    char* yb = (char*)d_out + (size_t)N * 64 * (f_out ? 4 : 2);
    int estride = (gridDim.x * 256) >> 3;
    for (long e = tid >> 3; e < E; e += estride) {
        bf16x8 mg = *reinterpret_cast<const bf16x8*>(M + e * 64 + c0);
        float ef[8]; ld8f(in.p[1], e * 64 + c0, f_ef, ef);
        float y[8];
        #pragma unroll
        for (int j = 0; j < 8; ++j) {
            float mv = bf2f(mg[j]);
            float t = (mv - mean[j]) * rstd[j] * ga[j] + be[j];
            float sl = t / (1.f + __expf(-t));
            y[j] = fin(ef[j] + sl);
        }
        if (f_out) {
            float* yp = (float*)yb + e * 64 + c0;
            f32x4 y0 = {y[0], y[1], y[2], y[3]}, y1 = {y[4], y[5], y[6], y[7]};
            *(f32x4*)yp = y0; *(f32x4*)(yp + 4) = y1;
        } else {
            bf16x8 yv;
            #pragma unroll
            for (int j = 0; j < 8; ++j) yv[j] = (bf16)y[j];
            *reinterpret_cast<bf16x8*>((bf16*)yb + e * 64 + c0) = yv;
        }
    }
}

extern "C" void kernel_launch(void* const* d_in, const int* in_sizes, int n_in,
                              void* d_out, int out_size, void* d_ws, size_t ws_size,
                              hipStream_t stream) {
    P22 p; I22 sz;
    for (int i = 0; i < 22; ++i) { p.p[i] = d_in[i]; sz.n[i] = in_sizes[i]; }
    const int N = in_sizes[0] / 64;
    const int E = in_sizes[2];

    char* ws = (char*)d_ws;
    size_t off = 0;
    auto alloc = [&](size_t bytes) -> void* {
        void* ptr = ws + off;
        off = (off + bytes + 255) & ~(size_t)255;
        return ptr;
    };
    int*   flags  = (int*)    alloc(22 * 4);
    bf16*  ESRC   = (bf16*)   alloc((size_t)N * 64 * 2);    // e_src values
    bf16*  EDST   = (bf16*)   alloc((size_t)N * 64 * 2);    // e_dst values
    ushort2* PG2  = (ushort2*)alloc((size_t)N * 64 * 4);    // (Bh, feat) per col
    float* el     = (float*)  alloc((size_t)N * 2 * 4);
    float* er     = (float*)  alloc((size_t)N * 2 * 4);
    bf16*  Wcat   = (bf16*)   alloc(64 * 256 * 2);
    float* bcat   = (float*)  alloc(256 * 4);
    bf16*  M      = (bf16*)   alloc((size_t)E * 64 * 2);    // full m (gated edge feature)
    int*   rowptr = (int*)    alloc((size_t)(N + 1) * 4);
    int*   cursor = (int*)    alloc((size_t)N * 4);
    int2*  ES     = (int2*)   alloc((size_t)E * 8);         // dst-sorted {e, src}
    float* v      = (float*)  alloc((size_t)N * 64 * 4);    // pre-BN node values
    char* zbase = ws + off;
    int*   deg      = (int*)  alloc((size_t)N * 4);
    float* bn_e_acc = (float*)alloc(128 * 4);
    float* bn_n_acc = (float*)alloc(128 * 4);
    size_t zbytes = (size_t)((ws + off) - zbase);
    hipMemsetAsync(zbase, 0, zbytes, stream);

    const int* srcp = (const int*)d_in[2];
    const int* dstp = (const int*)d_in[3];

    hipLaunchKernelGGL(k_detect, dim3(22), dim3(64), 0, stream, p, sz, flags);
    hipLaunchKernelGGL(k_prep, dim3(1), dim3(256), 0, stream, p, flags, Wcat, bcat);
    hipLaunchKernelGGL(k_node_gemm, dim3(800), dim3(256), 0, stream,
                       p, flags, Wcat, bcat, ESRC, EDST, PG2, el, er, N);
    hipLaunchKernelGGL(k_edge_gemm, dim3(1024), dim3(256), 0, stream,
                       p, flags, ESRC, EDST, M, deg, bn_e_acc, E);
    hipLaunchKernelGGL(k_scan, dim3(1), dim3(1024), 0, stream, deg, rowptr, cursor, N);
    hipLaunchKernelGGL(k_scatter, dim3(1024), dim3(256), 0, stream, srcp, dstp, cursor, ES, E);
    hipLaunchKernelGGL(k_agg, dim3(2048), dim3(256), 0, stream,
                       p, flags, PG2, M, el, er, rowptr, ES, v, bn_n_acc, N);
    hipLaunchKernelGGL(k_x_out, dim3(512), dim3(256), 0, stream, p, flags, v, bn_n_acc, d_out, N);
    hipLaunchKernelGGL(k_edge_y, dim3(2048), dim3(256), 0, stream,
                       p, flags, M, bn_e_acc, d_out, N, E);
}